// Round 2
// baseline (416.694 us; speedup 1.0000x reference)
//
#include <hip/hip_runtime.h>

// MakeCutouts: out[(n*B+b), c, i, j] = x[b, c, oy[n] + i*sz[n]/224, ox[n] + j*sz[n]/224]
// B=16, C=3, H=W=512, CUTN=32, CUT_SIZE=224. Output fp32 = 308 MB -> write-bound.
//
// Strategy: per-block LDS staging. One block per (n, plane, 8-row chunk).
//  - Stage the 8 used input rows (full 512 floats each) with dense float4
//    loads: 100% cache-line utilization, no divergent addressing.
//  - Gather from LDS: lane-stride sz/224 in [1, 2.29] words -> <=3-way bank
//    alias, which is ~free on gfx950 (2-way measured free).
//  - Column index xc is computed ONCE per thread (j fixed across the 8 rows).
//  - Stores: consecutive lanes -> consecutive dwords, coalesced.

#define CUT_SIZE 224
#define CUTN     32
#define BATCH    16
#define CHAN     3
#define HEIGHT   512
#define WIDTH    512
#define R_       8                       // output rows per block
#define CHUNKS   (CUT_SIZE / R_)         // 28
#define PLANES   (BATCH * CHAN)          // 48

__global__ __launch_bounds__(256, 8) void make_cutouts_kernel(
    const float* __restrict__ x,
    const int*   __restrict__ sizes,
    const int*   __restrict__ offsetx,
    const int*   __restrict__ offsety,
    float*       __restrict__ out)
{
    __shared__ float smem[R_ * WIDTH];   // 16 KB -> 8 blocks/CU, 32 waves/CU

    const int bid   = blockIdx.x;
    const int chunk = bid % CHUNKS;              // fastest: consecutive blocks
    const int t2    = bid / CHUNKS;              //   share the same input plane
    const int bc    = t2 % PLANES;
    const int n     = t2 / PLANES;

    const int sz = sizes[n];     // uniform per block -> scalar regs
    const int ox = offsetx[n];
    const int oy = offsety[n];
    const int i0 = chunk * R_;

    const int tid = threadIdx.x;

    // ---- Stage R_ input rows into LDS with dense float4 loads ----
    // 8 rows * 128 float4 = 1024 float4 -> 4 per thread.
    const float4* plane = (const float4*)(x + (size_t)bc * (HEIGHT * WIDTH));
    float4* s4 = (float4*)smem;
    #pragma unroll
    for (int k = 0; k < (R_ * (WIDTH / 4)) / 256; ++k) {   // 4 iterations
        const int idx = tid + k * 256;
        const int r   = idx >> 7;          // 128 float4 per row
        const int c4  = idx & 127;
        // (i0+r)*sz <= 223*512 fits in 24 bits; /224 lowers to magic mul.
        const int yy  = oy + ((i0 + r) * sz) / CUT_SIZE;
        s4[r * (WIDTH / 4) + c4] = plane[yy * (WIDTH / 4) + c4];
    }
    __syncthreads();

    // ---- Gather from LDS, coalesced store ----
    if (tid < CUT_SIZE) {
        const int j  = tid;
        const int xc = ox + (j * sz) / CUT_SIZE;   // fixed per thread
        float* o = out + (size_t)(n * PLANES + bc) * (CUT_SIZE * CUT_SIZE)
                       + (size_t)i0 * CUT_SIZE + j;
        #pragma unroll
        for (int r = 0; r < R_; ++r) {
            o[r * CUT_SIZE] = smem[r * WIDTH + xc];
        }
    }
}

extern "C" void kernel_launch(void* const* d_in, const int* in_sizes, int n_in,
                              void* d_out, int out_size, void* d_ws, size_t ws_size,
                              hipStream_t stream) {
    const float* x       = (const float*)d_in[0];
    const int*   sizes   = (const int*)d_in[1];
    const int*   offsetx = (const int*)d_in[2];
    const int*   offsety = (const int*)d_in[3];
    float*       out     = (float*)d_out;

    const int grid = CUTN * PLANES * CHUNKS;   // 32*48*28 = 43,008 blocks
    make_cutouts_kernel<<<grid, 256, 0, stream>>>(x, sizes, offsetx, offsety, out);
}